// Round 13
// baseline (56.638 us; speedup 1.0000x reference)
//
#include <hip/hip_runtime.h>
#include <math.h>

#define HS 64
#define WS 208
#define HF 128
#define WF 416
#define NS (HS * WS)   // 13312
#define KH 20
#define KS 41
#define KK (KS * KS)   // 1681
#define TW 8           // tile width in pixels
#define TH 8           // tile height in pixels
#define NBX (WS / TW)  // 26
#define NBY (HS / TH)  // 8
#define NBLK (NBX * NBY) // 208
#define TROW 48        // union rows staged
#define TCOL 48        // union cols staged
#define PITCH 49       // float4 row pitch
#define GEL (KS * TCOL) // per-wave element set: 41 rows x 48 cols = 1968
#define NIT 31         // 1968 = 30*64 + 48 -> 31 iters, last has 48 lanes
#define LOG2E 1.442695040888963f

// align_corners grid: f32 coords exactly as _resize_ac (arange(f32) * (f32(in-1)/f32(out-1))).
__device__ __forceinline__ void ac_idx(int o, int inN, float sc, int& i0, int& i1, float& w) {
#pragma clang fp contract(off)
    float s = (float)o * sc;
    float f = floorf(s);
    i0 = (int)f;
    i1 = min(i0 + 1, inN - 1);
    w = s - f;
}

// Fused kernel: one block per 8x8 pixel tile; one WAVE per pixel-row (8 pixels).
// Each ray element is read from LDS ONCE per wave and dotted against all 8 pixel
// directions (in VGPRs). No launch_bounds min-waves -> VGPR cap 256, no spills.
__global__ __launch_bounds__(512) void k_fused(const float* __restrict__ R,
                                               const float* __restrict__ X,
                                               const int* __restrict__ prog,
                                               float* __restrict__ xn,
                                               float* __restrict__ yn) {
#pragma clang fp contract(off)
    __shared__ float4 tile[TROW * PITCH];
    __shared__ float4 dirs[64];
    __shared__ float Tsh;

    int t = (int)threadIdx.x;
    int lane = t & 63;
    int py = t >> 6;                       // wave index == pixel row within tile
    int blk = (int)blockIdx.x;
    int by = blk / NBX, bx = blk - by * NBX;
    int ph0 = by * TH, pw0 = bx * TW;
    int srow_min = min(max(ph0 - KH, 0), HS - 1 - 2 * KH);
    int scol_min = min(max(pw0 - KH, 0), WS - 1 - 2 * KH);

    // ---- stage ray union tile (bit-exact f32 resize of R, mul/mul/add, no FMA) ----
    for (int e = t; e < TROW * TCOL; e += 512) {
        int i = e / TCOL, j = e - i * TCOL;
        int g = srow_min + i, cg = scol_min + j;
        if (g < HS && cg < WS) {
            int y0, y1, x0, x1; float wy, wx;
            ac_idx(g, HF, 127.0f / 63.0f, y0, y1, wy);
            ac_idx(cg, WF, 415.0f / 207.0f, x0, x1, wx);
            float omwy = 1.0f - wy, omwx = 1.0f - wx;
            float r[3];
#pragma unroll
            for (int c = 0; c < 3; ++c) {
                const float* p = R + c * (HF * WF);
                float v00 = p[y0 * WF + x0], v10 = p[y1 * WF + x0];
                float v01 = p[y0 * WF + x1], v11 = p[y1 * WF + x1];
                float a0 = v00 * omwy; float b0 = v10 * wy; float t0 = a0 + b0;
                float a1 = v01 * omwy; float b1 = v11 * wy; float t1 = a1 + b1;
                float c0 = t0 * omwx; float c1 = t1 * wx;
                r[c] = c0 + c1;
            }
            tile[i * PITCH + j] = make_float4(r[0], r[1], r[2], 0.0f);
        }
    }
    // ---- directions for the 64 tile pixels (bit-exact resize of X + normalize) ----
    if (t < 64) {
        int qy = t >> 3, qx = t & 7;
        int h = ph0 + qy, w = pw0 + qx;
        int y0, y1, x0, x1; float wy, wx;
        ac_idx(h, HF, 127.0f / 63.0f, y0, y1, wy);
        ac_idx(w, WF, 415.0f / 207.0f, x0, x1, wx);
        float omwy = 1.0f - wy, omwx = 1.0f - wx;
        float d[3];
#pragma unroll
        for (int c = 0; c < 3; ++c) {
            const float* q = X + c * (HF * WF);
            float u00 = q[y0 * WF + x0], u10 = q[y1 * WF + x0];
            float u01 = q[y0 * WF + x1], u11 = q[y1 * WF + x1];
            float e0 = u00 * omwy; float f0 = u10 * wy; float s0 = e0 + f0;
            float e1 = u01 * omwy; float f1 = u11 * wy; float s1 = e1 + f1;
            float g0 = s0 * omwx; float g1 = s1 * wx;
            d[c] = g0 + g1;
        }
        float q0 = d[0] * d[0]; float q1 = d[1] * d[1]; float q2 = d[2] * d[2];
        float ssq = (q0 + q1) + q2;
        float nrm = (float)sqrt((double)ssq);   // correctly-rounded f32 sqrt
        dirs[t] = make_float4(d[0] / nrm, d[1] / nrm, d[2] / nrm, 0.0f);
    }
    if (t == 0) {
        double T64 = fmax(1e-8, 1e-4 / exp(0.1 * (double)prog[0]));
        Tsh = (float)T64;   // same bits as np.float32(max(1e-8, 1e-4/exp(...)))
    }
    __syncthreads();

    // ---- per-wave setup: 8 pixel directions in VGPRs, col window starts ----
    int h = ph0 + py;
    int srow_g = min(max(h - KH, 0), HS - 1 - 2 * KH);
    int I0 = srow_g - srow_min;            // 0..7
    float d0[8], d1[8], d2[8];
    int J0[8];
#pragma unroll
    for (int px = 0; px < 8; ++px) {
        float4 dv = dirs[py * 8 + px];
        d0[px] = dv.x; d1[px] = dv.y; d2[px] = dv.z;
        int w = pw0 + px;
        J0[px] = min(max(w - KH, 0), WS - 1 - 2 * KH) - scol_min;   // 0..7
    }
    float Tf = Tsh;

    // ---- pass 1: lane sweeps elements e = lane + 64*it over 41x48 row-union;
    //      each element: 1 LDS read, 8 bit-exact dots; running max + flag bit ----
    float m[8];
    unsigned msk[8];
#pragma unroll
    for (int px = 0; px < 8; ++px) { m[px] = -INFINITY; msk[px] = 0u; }
#pragma unroll
    for (int it = 0; it < NIT; ++it) {
        int e = lane + 64 * it;
        if (it < NIT - 1 || lane < GEL - 64 * (NIT - 1)) {
            int rho = (e * 683) >> 15;     // exact floor(e/48) for e < 2048
            int J = e - rho * TCOL;
            float4 v = tile[(I0 + rho) * PITCH + J];
#pragma unroll
            for (int px = 0; px < 8; ++px) {
                float p0 = d0[px] * v.x; float p1 = d1[px] * v.y; float p2 = d2[px] * v.z;
                float l = (p0 + p1) + p2;
                int c = J - J0[px];
                bool valid = (unsigned)c <= 40u;
                float lv = valid ? l : -INFINITY;
                bool f = lv > (m[px] - 0.004f);    // superset of final survivors
                msk[px] |= f ? (1u << it) : 0u;
                m[px] = fmaxf(m[px], lv);
            }
        }
    }
    // wave butterfly max -> all lanes hold the full-window max per px
#pragma unroll
    for (int s = 1; s < 64; s <<= 1) {
#pragma unroll
        for (int px = 0; px < 8; ++px) m[px] = fmaxf(m[px], __shfl_xor(m[px], s));
    }

    // ---- pass 2: ffs-walk flagged bits only; exact IEEE div + exp2.
    //      (flagged => was valid; stale flags fail the final l > th test) ----
    float se[8], sr[8], sc[8];
#pragma unroll
    for (int px = 0; px < 8; ++px) { se[px] = 0.f; sr[px] = 0.f; sc[px] = 0.f; }
#pragma unroll
    for (int px = 0; px < 8; ++px) {
        float th = m[px] - 0.004f;     // below: z-zm < -108 -> f32 weight exactly 0
        float zm = m[px] / Tf;         // monotone div: == ref's max-of-(l/T)
        unsigned w8 = msk[px];
        while (w8) {
            int it = __ffs(w8) - 1;
            w8 &= w8 - 1;
            int e = lane + 64 * it;
            int rho = (e * 683) >> 15;
            int J = e - rho * TCOL;
            float4 v = tile[(I0 + rho) * PITCH + J];
            float p0 = d0[px] * v.x; float p1 = d1[px] * v.y; float p2 = d2[px] * v.z;
            float l = (p0 + p1) + p2;
            if (l > th) {
                float z = l / Tf;         // bit-identical to ref's logits/T
                float e2 = __builtin_amdgcn_exp2f((z - zm) * LOG2E);
                se[px] += e2;
                sr[px] += e2 * (float)(srow_g + rho);
                sc[px] += e2 * (float)(scol_min + J);
            }
        }
    }
    // butterfly sum; lane 0 then owns statically-indexed totals for all 8 px
#pragma unroll
    for (int s = 1; s < 64; s <<= 1) {
#pragma unroll
        for (int px = 0; px < 8; ++px) {
            se[px] += __shfl_xor(se[px], s);
            sr[px] += __shfl_xor(sr[px], s);
            sc[px] += __shfl_xor(sc[px], s);
        }
    }
    if (lane == 0) {
#pragma unroll
        for (int px = 0; px < 8; ++px) {
            int pix = h * WS + (pw0 + px);
            double ix = (double)sr[px] / (double)se[px];
            double iy = (double)sc[px] / (double)se[px];
            xn[pix] = (float)(2.0 * ix / (double)(HS - 1) - 1.0);
            yn[pix] = (float)(2.0 * iy / (double)(WS - 1) - 1.0);
        }
    }
}

// Bilinear upsample (align_corners) of (Yn, Xn) to full res, interleaved channels.
__global__ void k_up(const float* __restrict__ xn, const float* __restrict__ yn,
                     float* __restrict__ out) {
#pragma clang fp contract(off)
    int i = blockIdx.x * blockDim.x + threadIdx.x;
    if (i >= HF * WF) return;
    int hh = i / WF, ww = i - hh * WF;
    int y0, y1, x0, x1; float wy, wx;
    ac_idx(hh, HS, 63.0f / 127.0f, y0, y1, wy);
    ac_idx(ww, WS, 207.0f / 415.0f, x0, x1, wx);
    float omwy = 1.0f - wy, omwx = 1.0f - wx;
    float a0, b0, t0, t1;
    a0 = xn[y0 * WS + x0] * omwy; b0 = xn[y1 * WS + x0] * wy; t0 = a0 + b0;
    a0 = xn[y0 * WS + x1] * omwy; b0 = xn[y1 * WS + x1] * wy; t1 = a0 + b0;
    float bx = t0 * omwx + t1 * wx;     // Xn upsampled
    a0 = yn[y0 * WS + x0] * omwy; b0 = yn[y1 * WS + x0] * wy; t0 = a0 + b0;
    a0 = yn[y0 * WS + x1] * omwy; b0 = yn[y1 * WS + x1] * wy; t1 = a0 + b0;
    float ay = t0 * omwx + t1 * wx;     // Yn upsampled
    out[2 * i]     = ay;
    out[2 * i + 1] = bx;
}

extern "C" void kernel_launch(void* const* d_in, const int* in_sizes, int n_in,
                              void* d_out, int out_size, void* d_ws, size_t ws_size,
                              hipStream_t stream) {
    const float* R = (const float*)d_in[0];
    const float* X = (const float*)d_in[1];
    const int* prog = (const int*)d_in[2];
    float* xn = (float*)d_ws;        // NS
    float* yn = xn + NS;             // NS
    float* out = (float*)d_out;

    k_fused<<<NBLK, 512, 0, stream>>>(R, X, prog, xn, yn);
    k_up<<<(HF * WF + 255) / 256, 256, 0, stream>>>(xn, yn, out);
}

// Round 14
// 37.631 us; speedup vs baseline: 1.5051x; 1.5051x over previous
//
#include <hip/hip_runtime.h>
#include <math.h>

#define HS 64
#define WS 208
#define HF 128
#define WF 416
#define NS (HS * WS)   // 13312
#define KH 20
#define KS 41
#define KK (KS * KS)   // 1681
#define TW 8           // tile width in pixels
#define TH 4           // tile height in pixels
#define NBX (WS / TW)  // 26
#define NBY (HS / TH)  // 16
#define NBLK (NBX * NBY) // 416
#define TROW 44        // union rows staged (4-1+41)
#define TCOL 48        // union cols staged (8-1+41)
#define PITCH 49       // float4 row pitch
#define QCOL 44        // per-wave quad col-union (4-1+41)
#define GEL2 (KS * QCOL) // per-wave element set: 41 x 44 = 1804
#define NIT 29         // 1804 = 28*64 + 12 -> 29 iters, last has 12 lanes
#define LOG2E 1.442695040888963f

// align_corners grid: f32 coords exactly as _resize_ac (arange(f32) * (f32(in-1)/f32(out-1))).
__device__ __forceinline__ void ac_idx(int o, int inN, float sc, int& i0, int& i1, float& w) {
#pragma clang fp contract(off)
    float s = (float)o * sc;
    float f = floorf(s);
    i0 = (int)f;
    i1 = min(i0 + 1, inN - 1);
    w = s - f;
}

// Fused kernel: one block per 4x8 pixel tile; one WAVE per 4 horizontally-adjacent
// pixels (wave = pixel-row x col-half). Each ray element read from LDS once per wave,
// dotted against 4 directions in VGPRs. Small state -> no spills.
__global__ __launch_bounds__(512) void k_fused(const float* __restrict__ R,
                                               const float* __restrict__ X,
                                               const int* __restrict__ prog,
                                               float* __restrict__ xn,
                                               float* __restrict__ yn) {
#pragma clang fp contract(off)
    __shared__ float4 tile[TROW * PITCH];
    __shared__ float4 dirs[32];
    __shared__ float Tsh;

    int t = (int)threadIdx.x;
    int lane = t & 63;
    int wv = t >> 6;                       // 0..7
    int py = wv >> 1;                      // pixel row within tile 0..3
    int hx = wv & 1;                       // col half 0..1
    int blk = (int)blockIdx.x;
    int by = blk / NBX, bx = blk - by * NBX;
    int ph0 = by * TH, pw0 = bx * TW;
    int srow_min = min(max(ph0 - KH, 0), HS - 1 - 2 * KH);
    int scol_min = min(max(pw0 - KH, 0), WS - 1 - 2 * KH);

    // ---- stage ray union tile (bit-exact f32 resize of R, mul/mul/add, no FMA) ----
    for (int e = t; e < TROW * TCOL; e += 512) {
        int i = e / TCOL, j = e - i * TCOL;
        int g = srow_min + i, cg = scol_min + j;
        if (g < HS && cg < WS) {
            int y0, y1, x0, x1; float wy, wx;
            ac_idx(g, HF, 127.0f / 63.0f, y0, y1, wy);
            ac_idx(cg, WF, 415.0f / 207.0f, x0, x1, wx);
            float omwy = 1.0f - wy, omwx = 1.0f - wx;
            float r[3];
#pragma unroll
            for (int c = 0; c < 3; ++c) {
                const float* p = R + c * (HF * WF);
                float v00 = p[y0 * WF + x0], v10 = p[y1 * WF + x0];
                float v01 = p[y0 * WF + x1], v11 = p[y1 * WF + x1];
                float a0 = v00 * omwy; float b0 = v10 * wy; float t0 = a0 + b0;
                float a1 = v01 * omwy; float b1 = v11 * wy; float t1 = a1 + b1;
                float c0 = t0 * omwx; float c1 = t1 * wx;
                r[c] = c0 + c1;
            }
            tile[i * PITCH + j] = make_float4(r[0], r[1], r[2], 0.0f);
        }
    }
    // ---- directions for the 32 tile pixels (bit-exact resize of X + normalize) ----
    if (t < 32) {
        int qy = t >> 3, qx = t & 7;
        int h = ph0 + qy, w = pw0 + qx;
        int y0, y1, x0, x1; float wy, wx;
        ac_idx(h, HF, 127.0f / 63.0f, y0, y1, wy);
        ac_idx(w, WF, 415.0f / 207.0f, x0, x1, wx);
        float omwy = 1.0f - wy, omwx = 1.0f - wx;
        float d[3];
#pragma unroll
        for (int c = 0; c < 3; ++c) {
            const float* q = X + c * (HF * WF);
            float u00 = q[y0 * WF + x0], u10 = q[y1 * WF + x0];
            float u01 = q[y0 * WF + x1], u11 = q[y1 * WF + x1];
            float e0 = u00 * omwy; float f0 = u10 * wy; float s0 = e0 + f0;
            float e1 = u01 * omwy; float f1 = u11 * wy; float s1 = e1 + f1;
            float g0 = s0 * omwx; float g1 = s1 * wx;
            d[c] = g0 + g1;
        }
        float q0 = d[0] * d[0]; float q1 = d[1] * d[1]; float q2 = d[2] * d[2];
        float ssq = (q0 + q1) + q2;
        float nrm = (float)sqrt((double)ssq);   // correctly-rounded f32 sqrt
        dirs[t] = make_float4(d[0] / nrm, d[1] / nrm, d[2] / nrm, 0.0f);
    }
    if (t == 0) {
        double T64 = fmax(1e-8, 1e-4 / exp(0.1 * (double)prog[0]));
        Tsh = (float)T64;   // same bits as np.float32(max(1e-8, 1e-4/exp(...)))
    }
    __syncthreads();

    // ---- per-wave setup: 4 directions in VGPRs, col-window deltas ----
    int h = ph0 + py;
    int srow_g = min(max(h - KH, 0), HS - 1 - 2 * KH);
    int I0 = srow_g - srow_min;            // 0..3
    float d0[4], d1[4], d2[4];
    int J0q[4];
#pragma unroll
    for (int i = 0; i < 4; ++i) {
        int px = hx * 4 + i;
        float4 dv = dirs[py * 8 + px];
        d0[i] = dv.x; d1[i] = dv.y; d2[i] = dv.z;
        int w = pw0 + px;
        J0q[i] = min(max(w - KH, 0), WS - 1 - 2 * KH) - scol_min;   // 0..7
    }
    int J0g = J0q[0];                      // leftmost (J0 nondecreasing)
    int dJ0 = J0q[0] - J0g, dJ1 = J0q[1] - J0g, dJ2 = J0q[2] - J0g, dJ3 = J0q[3] - J0g;
    float Tf = Tsh;

    // ---- pass 1: lane sweeps e = lane + 64*it over 41x44 quad-union;
    //      1 LDS read, 4 bit-exact dots, validity mask, running max + flag bit ----
    float m[4];
    unsigned msk[4];
#pragma unroll
    for (int i = 0; i < 4; ++i) { m[i] = -INFINITY; msk[i] = 0u; }
#pragma unroll
    for (int it = 0; it < NIT; ++it) {
        int e = lane + 64 * it;
        if (it < NIT - 1 || lane < GEL2 - 64 * (NIT - 1)) {
            int rho = (e * 745) >> 15;     // exact floor(e/44) for e <= 2727
            int jl = e - rho * QCOL;
            float4 v = tile[(I0 + rho) * PITCH + J0g + jl];
#pragma unroll
            for (int i = 0; i < 4; ++i) {
                int dj = (i == 0) ? dJ0 : (i == 1) ? dJ1 : (i == 2) ? dJ2 : dJ3;
                float p0 = d0[i] * v.x; float p1 = d1[i] * v.y; float p2 = d2[i] * v.z;
                float l = (p0 + p1) + p2;
                int c = jl - dj;
                bool valid = (unsigned)c <= 40u;
                float lv = valid ? l : -INFINITY;
                bool f = lv > (m[i] - 0.004f);     // superset of final survivors
                msk[i] |= f ? (1u << it) : 0u;
                m[i] = fmaxf(m[i], lv);
            }
        }
    }
    // wave butterfly max -> all lanes hold each pixel's window max
#pragma unroll
    for (int s = 1; s < 64; s <<= 1) {
#pragma unroll
        for (int i = 0; i < 4; ++i) m[i] = fmaxf(m[i], __shfl_xor(m[i], s));
    }

    // ---- pass 2: ffs-walk flagged bits; exact IEEE div + exp2 ----
    float se[4], sr[4], sc[4];
#pragma unroll
    for (int i = 0; i < 4; ++i) { se[i] = 0.f; sr[i] = 0.f; sc[i] = 0.f; }
#pragma unroll
    for (int i = 0; i < 4; ++i) {
        float th = m[i] - 0.004f;      // below: z-zm < -108 -> f32 weight exactly 0
        float zm = m[i] / Tf;          // monotone div: == ref's max-of-(l/T)
        unsigned w8 = msk[i];
        while (w8) {
            int it = __ffs(w8) - 1;
            w8 &= w8 - 1;
            int e = lane + 64 * it;
            int rho = (e * 745) >> 15;
            int jl = e - rho * QCOL;
            float4 v = tile[(I0 + rho) * PITCH + J0g + jl];
            float p0 = d0[i] * v.x; float p1 = d1[i] * v.y; float p2 = d2[i] * v.z;
            float l = (p0 + p1) + p2;  // flagged => was valid (in-window)
            if (l > th) {
                float z = l / Tf;      // bit-identical to ref's logits/T
                float e2 = __builtin_amdgcn_exp2f((z - zm) * LOG2E);
                se[i] += e2;
                sr[i] += e2 * (float)(srow_g + rho);
                sc[i] += e2 * (float)(scol_min + J0g + jl);
            }
        }
    }
    // butterfly sum; lane 0 owns statically-indexed totals for the 4 px
#pragma unroll
    for (int s = 1; s < 64; s <<= 1) {
#pragma unroll
        for (int i = 0; i < 4; ++i) {
            se[i] += __shfl_xor(se[i], s);
            sr[i] += __shfl_xor(sr[i], s);
            sc[i] += __shfl_xor(sc[i], s);
        }
    }
    if (lane == 0) {
#pragma unroll
        for (int i = 0; i < 4; ++i) {
            int pix = h * WS + (pw0 + hx * 4 + i);
            double ix = (double)sr[i] / (double)se[i];
            double iy = (double)sc[i] / (double)se[i];
            xn[pix] = (float)(2.0 * ix / (double)(HS - 1) - 1.0);
            yn[pix] = (float)(2.0 * iy / (double)(WS - 1) - 1.0);
        }
    }
}

// Bilinear upsample (align_corners) of (Yn, Xn) to full res, interleaved channels.
__global__ void k_up(const float* __restrict__ xn, const float* __restrict__ yn,
                     float* __restrict__ out) {
#pragma clang fp contract(off)
    int i = blockIdx.x * blockDim.x + threadIdx.x;
    if (i >= HF * WF) return;
    int hh = i / WF, ww = i - hh * WF;
    int y0, y1, x0, x1; float wy, wx;
    ac_idx(hh, HS, 63.0f / 127.0f, y0, y1, wy);
    ac_idx(ww, WS, 207.0f / 415.0f, x0, x1, wx);
    float omwy = 1.0f - wy, omwx = 1.0f - wx;
    float a0, b0, t0, t1;
    a0 = xn[y0 * WS + x0] * omwy; b0 = xn[y1 * WS + x0] * wy; t0 = a0 + b0;
    a0 = xn[y0 * WS + x1] * omwy; b0 = xn[y1 * WS + x1] * wy; t1 = a0 + b0;
    float bx = t0 * omwx + t1 * wx;     // Xn upsampled
    a0 = yn[y0 * WS + x0] * omwy; b0 = yn[y1 * WS + x0] * wy; t0 = a0 + b0;
    a0 = yn[y0 * WS + x1] * omwy; b0 = yn[y1 * WS + x1] * wy; t1 = a0 + b0;
    float ay = t0 * omwx + t1 * wx;     // Yn upsampled
    out[2 * i]     = ay;
    out[2 * i + 1] = bx;
}

extern "C" void kernel_launch(void* const* d_in, const int* in_sizes, int n_in,
                              void* d_out, int out_size, void* d_ws, size_t ws_size,
                              hipStream_t stream) {
    const float* R = (const float*)d_in[0];
    const float* X = (const float*)d_in[1];
    const int* prog = (const int*)d_in[2];
    float* xn = (float*)d_ws;        // NS
    float* yn = xn + NS;             // NS
    float* out = (float*)d_out;

    k_fused<<<NBLK, 512, 0, stream>>>(R, X, prog, xn, yn);
    k_up<<<(HF * WF + 255) / 256, 256, 0, stream>>>(xn, yn, out);
}

// Round 15
// 33.327 us; speedup vs baseline: 1.6995x; 1.1292x over previous
//
#include <hip/hip_runtime.h>
#include <math.h>

#define HS 64
#define WS 208
#define HF 128
#define WF 416
#define NS (HS * WS)   // 13312
#define KH 20
#define KS 41
#define KK (KS * KS)   // 1681
#define NJ2 7          // ceil(1681/256); last iter: tid<145 live
#define GRID 2048      // persistent blocks: 8 per CU
#define LOG2E 1.442695040888963f

// align_corners grid: f32 coords exactly as _resize_ac (arange(f32) * (f32(in-1)/f32(out-1))).
__device__ __forceinline__ void ac_idx(int o, int inN, float sc, int& i0, int& i1, float& w) {
#pragma clang fp contract(off)
    float s = (float)o * sc;
    float f = floorf(s);
    i0 = (int)f;
    i1 = min(i0 + 1, inN - 1);
    w = s - f;
}

// k_down: bit-faithful f32 resize of R -> ray4 (padded float4 triples) and of X ->
// normalized dir4; thread 0 also computes the f32 temperature.
__global__ void k_down(const float* __restrict__ R, const float* __restrict__ X,
                       const int* __restrict__ prog,
                       float4* __restrict__ ray4, float4* __restrict__ dir4,
                       float* __restrict__ tbuf) {
#pragma clang fp contract(off)
    int n = blockIdx.x * blockDim.x + threadIdx.x;
    if (n >= NS) return;
    if (n == 0) {
        double T64 = fmax(1e-8, 1e-4 / exp(0.1 * (double)prog[0]));
        tbuf[0] = (float)T64;   // same bits as np.float32(max(1e-8, 1e-4/exp(...)))
    }
    int y = n / WS, x = n - y * WS;
    int y0, y1, x0, x1; float wy, wx;
    ac_idx(y, HF, 127.0f / 63.0f, y0, y1, wy);
    ac_idx(x, WF, 415.0f / 207.0f, x0, x1, wx);
    float omwy = 1.0f - wy, omwx = 1.0f - wx;
    float r[3], d[3];
#pragma unroll
    for (int c = 0; c < 3; ++c) {
        const float* p = R + c * (HF * WF);
        float v00 = p[y0 * WF + x0], v10 = p[y1 * WF + x0];
        float v01 = p[y0 * WF + x1], v11 = p[y1 * WF + x1];
        float a0 = v00 * omwy; float b0 = v10 * wy; float t0 = a0 + b0;
        float a1 = v01 * omwy; float b1 = v11 * wy; float t1 = a1 + b1;
        float c0 = t0 * omwx; float c1 = t1 * wx;
        r[c] = c0 + c1;
        const float* q = X + c * (HF * WF);
        float u00 = q[y0 * WF + x0], u10 = q[y1 * WF + x0];
        float u01 = q[y0 * WF + x1], u11 = q[y1 * WF + x1];
        float e0 = u00 * omwy; float f0 = u10 * wy; float s0 = e0 + f0;
        float e1 = u01 * omwy; float f1 = u11 * wy; float s1 = e1 + f1;
        float g0 = s0 * omwx; float g1 = s1 * wx;
        d[c] = g0 + g1;
    }
    float q0 = d[0] * d[0]; float q1 = d[1] * d[1]; float q2 = d[2] * d[2];
    float ssq = (q0 + q1) + q2;
    float nrm = (float)sqrt((double)ssq);   // correctly-rounded f32 sqrt
    ray4[n] = make_float4(r[0], r[1], r[2], 0.0f);
    dir4[n] = make_float4(d[0] / nrm, d[1] / nrm, d[2] / nrm, 0.0f);
}

// k_main: PERSISTENT blocks (2048 = 8/CU), each grid-strides over pixels; per pixel
// the body is byte-identical to the round-7 kernel (proven absmax 0.00390625).
__global__ __launch_bounds__(256, 6) void k_main(const float4* __restrict__ ray4,
                                                 const float4* __restrict__ dir4,
                                                 const float* __restrict__ tbuf,
                                                 float* __restrict__ xn,
                                                 float* __restrict__ yn) {
#pragma clang fp contract(off)
    int tid = (int)threadIdx.x;
    int lane = tid & 63;
    int wid = tid >> 6;
    int k1i = (tid * 25) >> 10;        // exact floor(tid/41) for tid<256
    int k2i = tid - k1i * KS;
    float Tf = tbuf[0];

    __shared__ float smax[4];
    __shared__ float ssum[4][3];

    for (int pix = (int)blockIdx.x; pix < NS; pix += GRID) {
        int h = pix / WS, w = pix - h * WS;
        int srow = min(max(h - KH, 0), HS - 1 - 2 * KH);
        int scol = min(max(w - KH, 0), WS - 1 - 2 * KH);

        float4 dv = dir4[pix];
        float d0 = dv.x, d1 = dv.y, d2 = dv.z;

        int off = (srow + k1i) * WS + scol + k2i;
        int colk = k2i;

        // Pass 1: raw logits, bit-exact ((p0+p1)+p2), running max. k += 256 = 6*41+10.
        float lg[NJ2];
        float m = -INFINITY;
#pragma unroll
        for (int j = 0; j < NJ2 - 1; ++j) {
            float4 v = ray4[off];
            float p0 = d0 * v.x; float p1 = d1 * v.y; float p2 = d2 * v.z;
            float l = (p0 + p1) + p2;
            lg[j] = l;
            m = fmaxf(m, l);
            int cn = colk + 10;
            bool cr = cn >= KS;
            colk = cr ? cn - KS : cn;
            off += cr ? (7 * WS - 31) : (6 * WS + 10);
        }
        {   // j=6: k = tid + 1536, live iff tid < 145
            float l = -INFINITY;
            if (tid < KK - 256 * (NJ2 - 1)) {
                float4 v = ray4[off];
                float p0 = d0 * v.x; float p1 = d1 * v.y; float p2 = d2 * v.z;
                l = (p0 + p1) + p2;
            }
            lg[NJ2 - 1] = l;
            m = fmaxf(m, l);
        }
#pragma unroll
        for (int s = 1; s < 64; s <<= 1) m = fmaxf(m, __shfl_xor(m, s));

        if (lane == 0) smax[wid] = m;
        __syncthreads();
        m = fmaxf(fmaxf(smax[0], smax[1]), fmaxf(smax[2], smax[3]));

        float zm = m / Tf;             // monotone div: == ref's max-of-(l/T)
        float thresh = m - 0.004f;     // below: z-zm < -108 -> f32 weight exactly 0

        // Pass 2: incremental (k1,k2) replay; only live-ballot iterations pay div+exp.
        float se = 0.f, sr = 0.f, sc = 0.f;
        int c1 = k1i, c2 = k2i;
#pragma unroll
        for (int j = 0; j < NJ2; ++j) {
            bool a = lg[j] > thresh;   // dead lanes hold -INF -> false
            if (__ballot(a)) {
                float z = lg[j] / Tf;  // bit-identical to ref's logits/T
                float arg = (z - zm) * LOG2E;
                float e = a ? __builtin_amdgcn_exp2f(arg) : 0.0f;
                se += e;
                sr += e * (float)(srow + c1);
                sc += e * (float)(scol + c2);
            }
            int cn = c2 + 10;
            bool cr = cn >= KS;
            c2 = cr ? cn - KS : cn;
            c1 += cr ? 7 : 6;
        }
#pragma unroll
        for (int s = 1; s < 64; s <<= 1) {
            se += __shfl_xor(se, s);
            sr += __shfl_xor(sr, s);
            sc += __shfl_xor(sc, s);
        }
        if (lane == 0) { ssum[wid][0] = se; ssum[wid][1] = sr; ssum[wid][2] = sc; }
        __syncthreads();
        if (tid == 0) {
            float SE = (ssum[0][0] + ssum[1][0]) + (ssum[2][0] + ssum[3][0]);
            float SR = (ssum[0][1] + ssum[1][1]) + (ssum[2][1] + ssum[3][1]);
            float SC = (ssum[0][2] + ssum[1][2]) + (ssum[2][2] + ssum[3][2]);
            double ix = (double)SR / (double)SE, iy = (double)SC / (double)SE;
            xn[pix] = (float)(2.0 * ix / (double)(HS - 1) - 1.0);
            yn[pix] = (float)(2.0 * iy / (double)(WS - 1) - 1.0);
        }
        // Race-freedom across pixel iterations: smax writes of iter i+1 happen after
        // the ssum __syncthreads of iter i; ssum writes of iter i+1 happen after the
        // smax __syncthreads of iter i+1, which tid0 joins only after its ssum reads.
    }
}

// Bilinear upsample (align_corners) of (Yn, Xn) to full res, interleaved channels.
__global__ void k_up(const float* __restrict__ xn, const float* __restrict__ yn,
                     float* __restrict__ out) {
#pragma clang fp contract(off)
    int i = blockIdx.x * blockDim.x + threadIdx.x;
    if (i >= HF * WF) return;
    int hh = i / WF, ww = i - hh * WF;
    int y0, y1, x0, x1; float wy, wx;
    ac_idx(hh, HS, 63.0f / 127.0f, y0, y1, wy);
    ac_idx(ww, WS, 207.0f / 415.0f, x0, x1, wx);
    float omwy = 1.0f - wy, omwx = 1.0f - wx;
    float a0, b0, t0, t1;
    a0 = xn[y0 * WS + x0] * omwy; b0 = xn[y1 * WS + x0] * wy; t0 = a0 + b0;
    a0 = xn[y0 * WS + x1] * omwy; b0 = xn[y1 * WS + x1] * wy; t1 = a0 + b0;
    float bx = t0 * omwx + t1 * wx;     // Xn upsampled
    a0 = yn[y0 * WS + x0] * omwy; b0 = yn[y1 * WS + x0] * wy; t0 = a0 + b0;
    a0 = yn[y0 * WS + x1] * omwy; b0 = yn[y1 * WS + x1] * wy; t1 = a0 + b0;
    float ay = t0 * omwx + t1 * wx;     // Yn upsampled
    out[2 * i]     = ay;
    out[2 * i + 1] = bx;
}

extern "C" void kernel_launch(void* const* d_in, const int* in_sizes, int n_in,
                              void* d_out, int out_size, void* d_ws, size_t ws_size,
                              hipStream_t stream) {
    const float* R = (const float*)d_in[0];
    const float* X = (const float*)d_in[1];
    const int* prog = (const int*)d_in[2];
    float4* ray4 = (float4*)d_ws;            // NS float4
    float4* dir4 = ray4 + NS;                // NS float4
    float* xn   = (float*)(dir4 + NS);       // NS
    float* yn   = xn + NS;                   // NS
    float* tbuf = yn + NS;                   // 1
    float* out  = (float*)d_out;

    k_down<<<(NS + 255) / 256, 256, 0, stream>>>(R, X, prog, ray4, dir4, tbuf);
    k_main<<<GRID, 256, 0, stream>>>(ray4, dir4, tbuf, xn, yn);   // persistent blocks
    k_up<<<(HF * WF + 255) / 256, 256, 0, stream>>>(xn, yn, out);
}

// Round 16
// 30.733 us; speedup vs baseline: 1.8429x; 1.0844x over previous
//
#include <hip/hip_runtime.h>
#include <math.h>

#define HS 64
#define WS 208
#define HF 128
#define WF 416
#define NS (HS * WS)   // 13312
#define KH 20
#define KS 41
#define KK (KS * KS)   // 1681
#define NJ2 7          // ceil(1681/256); last iter: tid<145 live
#define LOG2E 1.442695040888963f

// align_corners grid: f32 coords exactly as _resize_ac (arange(f32) * (f32(in-1)/f32(out-1))).
__device__ __forceinline__ void ac_idx(int o, int inN, float sc, int& i0, int& i1, float& w) {
#pragma clang fp contract(off)
    float s = (float)o * sc;
    float f = floorf(s);
    i0 = (int)f;
    i1 = min(i0 + 1, inN - 1);
    w = s - f;
}

// k_down: bit-faithful f32 resize of R -> ray4 (padded float4 triples) and of X ->
// normalized dir4; thread 0 also computes the f32 temperature.
__global__ void k_down(const float* __restrict__ R, const float* __restrict__ X,
                       const int* __restrict__ prog,
                       float4* __restrict__ ray4, float4* __restrict__ dir4,
                       float* __restrict__ tbuf) {
#pragma clang fp contract(off)
    int n = blockIdx.x * blockDim.x + threadIdx.x;
    if (n >= NS) return;
    if (n == 0) {
        double T64 = fmax(1e-8, 1e-4 / exp(0.1 * (double)prog[0]));
        tbuf[0] = (float)T64;   // same bits as np.float32(max(1e-8, 1e-4/exp(...)))
    }
    int y = n / WS, x = n - y * WS;
    int y0, y1, x0, x1; float wy, wx;
    ac_idx(y, HF, 127.0f / 63.0f, y0, y1, wy);
    ac_idx(x, WF, 415.0f / 207.0f, x0, x1, wx);
    float omwy = 1.0f - wy, omwx = 1.0f - wx;
    float r[3], d[3];
#pragma unroll
    for (int c = 0; c < 3; ++c) {
        const float* p = R + c * (HF * WF);
        float v00 = p[y0 * WF + x0], v10 = p[y1 * WF + x0];
        float v01 = p[y0 * WF + x1], v11 = p[y1 * WF + x1];
        float a0 = v00 * omwy; float b0 = v10 * wy; float t0 = a0 + b0;
        float a1 = v01 * omwy; float b1 = v11 * wy; float t1 = a1 + b1;
        float c0 = t0 * omwx; float c1 = t1 * wx;
        r[c] = c0 + c1;
        const float* q = X + c * (HF * WF);
        float u00 = q[y0 * WF + x0], u10 = q[y1 * WF + x0];
        float u01 = q[y0 * WF + x1], u11 = q[y1 * WF + x1];
        float e0 = u00 * omwy; float f0 = u10 * wy; float s0 = e0 + f0;
        float e1 = u01 * omwy; float f1 = u11 * wy; float s1 = e1 + f1;
        float g0 = s0 * omwx; float g1 = s1 * wx;
        d[c] = g0 + g1;
    }
    float q0 = d[0] * d[0]; float q1 = d[1] * d[1]; float q2 = d[2] * d[2];
    float ssq = (q0 + q1) + q2;
    float nrm = (float)sqrt((double)ssq);   // correctly-rounded f32 sqrt
    ray4[n] = make_float4(r[0], r[1], r[2], 0.0f);
    dir4[n] = make_float4(d[0] / nrm, d[1] / nrm, d[2] / nrm, 0.0f);
}

// One BLOCK (256 threads, 4 waves) per pixel; pass 1 restructured for explicit MLP:
// all 7 addresses computed upfront, all 7 dwordx4 loads issued back-to-back (one
// latency exposure), then 35 independent FP dots and a tree max.
__global__ __launch_bounds__(256) void k_main(const float4* __restrict__ ray4,
                                              const float4* __restrict__ dir4,
                                              const float* __restrict__ tbuf,
                                              float* __restrict__ xn, float* __restrict__ yn) {
#pragma clang fp contract(off)
    int pix = blockIdx.x;
    int tid = (int)threadIdx.x;
    int lane = tid & 63;
    int wid = tid >> 6;
    int h = pix / WS, w = pix - h * WS;
    int srow = min(max(h - KH, 0), HS - 1 - 2 * KH);
    int scol = min(max(w - KH, 0), WS - 1 - 2 * KH);

    float4 dv = dir4[pix];
    float d0 = dv.x, d1 = dv.y, d2 = dv.z;
    float Tf = tbuf[0];

    int k1i = (tid * 25) >> 10;        // exact floor(tid/41) for tid<256
    int k2i = tid - k1i * KS;

    // ---- phase A: all 7 addresses + (k1,k2) coords via cheap carry chain ----
    int offs[NJ2], cc1[NJ2], cc2[NJ2];
    {
        int off = (srow + k1i) * WS + scol + k2i;
        int colk = k2i, a1 = k1i;
#pragma unroll
        for (int j = 0; j < NJ2; ++j) {
            offs[j] = off; cc1[j] = a1; cc2[j] = colk;
            int cn = colk + 10;            // k += 256 = 6*41 + 10
            bool cr = cn >= KS;
            colk = cr ? cn - KS : cn;
            a1 += cr ? 7 : 6;
            off += cr ? (7 * WS - 31) : (6 * WS + 10);
        }
    }
    bool live6 = tid < KK - 256 * (NJ2 - 1);   // j=6 live iff tid < 145
    if (!live6) offs[NJ2 - 1] = 0;             // safe dummy address

    // ---- phase B: issue all 7 loads back-to-back (independent, one exposure) ----
    float4 v[NJ2];
#pragma unroll
    for (int j = 0; j < NJ2; ++j) v[j] = ray4[offs[j]];

    // ---- phase C: 7 independent bit-exact dots ((p0+p1)+p2), tree max ----
    float lg[NJ2];
#pragma unroll
    for (int j = 0; j < NJ2; ++j) {
        float p0 = d0 * v[j].x; float p1 = d1 * v[j].y; float p2 = d2 * v[j].z;
        lg[j] = (p0 + p1) + p2;
    }
    if (!live6) lg[NJ2 - 1] = -INFINITY;
    float m01 = fmaxf(lg[0], lg[1]);
    float m23 = fmaxf(lg[2], lg[3]);
    float m45 = fmaxf(lg[4], lg[5]);
    float m = fmaxf(fmaxf(m01, m23), fmaxf(m45, lg[6]));
#pragma unroll
    for (int s = 1; s < 64; s <<= 1) m = fmaxf(m, __shfl_xor(m, s));

    __shared__ float smax[4];
    __shared__ float ssum[4][3];
    if (lane == 0) smax[wid] = m;
    __syncthreads();
    m = fmaxf(fmaxf(smax[0], smax[1]), fmaxf(smax[2], smax[3]));

    float zm = m / Tf;                 // monotone div: == ref's max-of-(l/T)
    float thresh = m - 0.004f;         // below: z-zm < -108 -> f32 weight exactly 0

    // ---- pass 2: ballot-skip dead iterations; IEEE div z=l/Tf only on live ones ----
    float se = 0.f, sr = 0.f, sc = 0.f;
#pragma unroll
    for (int j = 0; j < NJ2; ++j) {
        bool a = lg[j] > thresh;       // dead lanes hold -INF -> false
        if (__ballot(a)) {
            float z = lg[j] / Tf;      // bit-identical to ref's logits/T
            float arg = (z - zm) * LOG2E;
            float e = a ? __builtin_amdgcn_exp2f(arg) : 0.0f;
            se += e;
            sr += e * (float)(srow + cc1[j]);
            sc += e * (float)(scol + cc2[j]);
        }
    }
#pragma unroll
    for (int s = 1; s < 64; s <<= 1) {
        se += __shfl_xor(se, s);
        sr += __shfl_xor(sr, s);
        sc += __shfl_xor(sc, s);
    }
    if (lane == 0) { ssum[wid][0] = se; ssum[wid][1] = sr; ssum[wid][2] = sc; }
    __syncthreads();
    if (tid == 0) {
        float SE = (ssum[0][0] + ssum[1][0]) + (ssum[2][0] + ssum[3][0]);
        float SR = (ssum[0][1] + ssum[1][1]) + (ssum[2][1] + ssum[3][1]);
        float SC = (ssum[0][2] + ssum[1][2]) + (ssum[2][2] + ssum[3][2]);
        double ix = (double)SR / (double)SE, iy = (double)SC / (double)SE;
        xn[pix] = (float)(2.0 * ix / (double)(HS - 1) - 1.0);
        yn[pix] = (float)(2.0 * iy / (double)(WS - 1) - 1.0);
    }
}

// Bilinear upsample (align_corners) of (Yn, Xn) to full res, interleaved channels.
__global__ void k_up(const float* __restrict__ xn, const float* __restrict__ yn,
                     float* __restrict__ out) {
#pragma clang fp contract(off)
    int i = blockIdx.x * blockDim.x + threadIdx.x;
    if (i >= HF * WF) return;
    int hh = i / WF, ww = i - hh * WF;
    int y0, y1, x0, x1; float wy, wx;
    ac_idx(hh, HS, 63.0f / 127.0f, y0, y1, wy);
    ac_idx(ww, WS, 207.0f / 415.0f, x0, x1, wx);
    float omwy = 1.0f - wy, omwx = 1.0f - wx;
    float a0, b0, t0, t1;
    a0 = xn[y0 * WS + x0] * omwy; b0 = xn[y1 * WS + x0] * wy; t0 = a0 + b0;
    a0 = xn[y0 * WS + x1] * omwy; b0 = xn[y1 * WS + x1] * wy; t1 = a0 + b0;
    float bx = t0 * omwx + t1 * wx;     // Xn upsampled
    a0 = yn[y0 * WS + x0] * omwy; b0 = yn[y1 * WS + x0] * wy; t0 = a0 + b0;
    a0 = yn[y0 * WS + x1] * omwy; b0 = yn[y1 * WS + x1] * wy; t1 = a0 + b0;
    float ay = t0 * omwx + t1 * wx;     // Yn upsampled
    out[2 * i]     = ay;
    out[2 * i + 1] = bx;
}

extern "C" void kernel_launch(void* const* d_in, const int* in_sizes, int n_in,
                              void* d_out, int out_size, void* d_ws, size_t ws_size,
                              hipStream_t stream) {
    const float* R = (const float*)d_in[0];
    const float* X = (const float*)d_in[1];
    const int* prog = (const int*)d_in[2];
    float4* ray4 = (float4*)d_ws;            // NS float4
    float4* dir4 = ray4 + NS;                // NS float4
    float* xn   = (float*)(dir4 + NS);       // NS
    float* yn   = xn + NS;                   // NS
    float* tbuf = yn + NS;                   // 1
    float* out  = (float*)d_out;

    k_down<<<(NS + 255) / 256, 256, 0, stream>>>(R, X, prog, ray4, dir4, tbuf);
    k_main<<<NS, 256, 0, stream>>>(ray4, dir4, tbuf, xn, yn);   // one block per pixel
    k_up<<<(HF * WF + 255) / 256, 256, 0, stream>>>(xn, yn, out);
}